// Round 1
// baseline (2273.145 us; speedup 1.0000x reference)
//
#include <hip/hip_runtime.h>
#include <hip/hip_bf16.h>

// Problem constants (B=2, S=2048, D=1024, F=4096, H=16, hd=64)
constexpr int Bb = 2, Ss = 2048, Dd = 1024, Ff = 4096, Hh = 16, HD = 64;
constexpr int Mm = Bb * Ss;  // 4096 token rows

__device__ __forceinline__ float gelu_exact(float x) {
    return 0.5f * x * (1.0f + erff(x * 0.70710678118654752f));
}

// ---------------------------------------------------------------------------
// C[M,N] = A[M,K] @ B[K,N] + bias[N], optional exact GELU.
// 128x128 tile, BK=16, 256 threads, 8x8 per-thread microtile (split 4+4 so
// 16 consecutive lanes read 256B contiguous from LDS -> conflict-free).
// ---------------------------------------------------------------------------
template <bool GELU>
__global__ __launch_bounds__(256) void gemm_bias(
    const float* __restrict__ A, const float* __restrict__ B,
    const float* __restrict__ bias, float* __restrict__ C,
    int M, int N, int K)
{
    constexpr int BM = 128, BN = 128, BK = 16;
    __shared__ float As[BK][BM];  // transposed: As[k][m]
    __shared__ float Bs[BK][BN];  // natural:    Bs[k][n]

    const int tid  = threadIdx.x;
    const int tx   = tid & 15;   // N direction (16)
    const int ty   = tid >> 4;   // M direction (16)
    const int brow = blockIdx.y * BM;
    const int bcol = blockIdx.x * BN;

    float acc[8][8];
#pragma unroll
    for (int i = 0; i < 8; ++i)
#pragma unroll
        for (int j = 0; j < 8; ++j) acc[i][j] = 0.f;

    // A tile load: 128 rows x 16 k-cols = 512 float4; 2 per thread.
    const int arow = tid >> 2;        // 0..63
    const int akof = (tid & 3) * 4;   // 0,4,8,12
    // B tile load: 16 k-rows x 128 cols = 512 float4; 2 per thread.
    const int bkrow = tid >> 5;       // 0..7
    const int bcof  = (tid & 31) * 4; // 0..124

    const float* aptr0 = A + (size_t)(brow + arow) * K + akof;
    const float* aptr1 = A + (size_t)(brow + arow + 64) * K + akof;
    const float* bptr0 = B + (size_t)bkrow * N + bcol + bcof;
    const float* bptr1 = B + (size_t)(bkrow + 8) * N + bcol + bcof;

    for (int k0 = 0; k0 < K; k0 += BK) {
        float4 a0 = *(const float4*)(aptr0 + k0);
        float4 a1 = *(const float4*)(aptr1 + k0);
        float4 b0 = *(const float4*)(bptr0 + (size_t)k0 * N);
        float4 b1 = *(const float4*)(bptr1 + (size_t)k0 * N);

        As[akof + 0][arow] = a0.x;
        As[akof + 1][arow] = a0.y;
        As[akof + 2][arow] = a0.z;
        As[akof + 3][arow] = a0.w;
        As[akof + 0][arow + 64] = a1.x;
        As[akof + 1][arow + 64] = a1.y;
        As[akof + 2][arow + 64] = a1.z;
        As[akof + 3][arow + 64] = a1.w;
        *(float4*)&Bs[bkrow][bcof]     = b0;
        *(float4*)&Bs[bkrow + 8][bcof] = b1;
        __syncthreads();

#pragma unroll
        for (int kk = 0; kk < BK; ++kk) {
            float a[8], b[8];
            *(float4*)&a[0] = *(const float4*)&As[kk][ty * 4];
            *(float4*)&a[4] = *(const float4*)&As[kk][64 + ty * 4];
            *(float4*)&b[0] = *(const float4*)&Bs[kk][tx * 4];
            *(float4*)&b[4] = *(const float4*)&Bs[kk][64 + tx * 4];
#pragma unroll
            for (int i = 0; i < 8; ++i)
#pragma unroll
                for (int j = 0; j < 8; ++j)
                    acc[i][j] = fmaf(a[i], b[j], acc[i][j]);
        }
        __syncthreads();
    }

    // Epilogue: bias (+GELU), vectorized stores.
#pragma unroll
    for (int ih = 0; ih < 2; ++ih) {
#pragma unroll
        for (int i = 0; i < 4; ++i) {
            const int r = brow + ih * 64 + ty * 4 + i;
#pragma unroll
            for (int jh = 0; jh < 2; ++jh) {
                const int c = bcol + jh * 64 + tx * 4;
                float4 o;
                o.x = acc[ih * 4 + i][jh * 4 + 0] + bias[c + 0];
                o.y = acc[ih * 4 + i][jh * 4 + 1] + bias[c + 1];
                o.z = acc[ih * 4 + i][jh * 4 + 2] + bias[c + 2];
                o.w = acc[ih * 4 + i][jh * 4 + 3] + bias[c + 3];
                if (GELU) {
                    o.x = gelu_exact(o.x);
                    o.y = gelu_exact(o.y);
                    o.z = gelu_exact(o.z);
                    o.w = gelu_exact(o.w);
                }
                *(float4*)(C + (size_t)r * N + c) = o;
            }
        }
    }
}

// ---------------------------------------------------------------------------
// Flash attention fp32. qkv layout: row = token, 3072 cols; head h occupies
// cols [h*192, h*192+192) as q|k|v of 64 each. Output attn[M, D], col=h*64+d.
// Block: one 64-row Q tile for one (b,h). 256 threads as 16x16, 4x4 each.
// K stored transposed in LDS so the scores loop is conflict-free.
// ---------------------------------------------------------------------------
__global__ __launch_bounds__(256) void flash_attn(
    const float* __restrict__ qkv, float* __restrict__ attn)
{
    constexpr int PAD = 4;
    __shared__ float Qs[64][HD + PAD];   // [q][d], pre-scaled by 1/8
    __shared__ float Kst[HD][64 + PAD];  // [d][k]  (transposed)
    __shared__ float Vs[64][HD + PAD];   // [k][d]
    __shared__ float Ps[64][64 + PAD];   // [q][k]

    const int tid = threadIdx.x;
    const int tx  = tid & 15;
    const int ty  = tid >> 4;
    const int qt  = blockIdx.x;        // 0..31
    const int b   = blockIdx.y >> 4;
    const int h   = blockIdx.y & 15;
    const size_t base = (size_t)b * Ss;
    const int qc = h * 192, kc = qc + 64, vc = qc + 128;

    // Load Q tile (scaled by 1/sqrt(hd) = 0.125)
#pragma unroll
    for (int rep = 0; rep < 4; ++rep) {
        int idx = rep * 256 + tid;
        int r = idx >> 4;
        int c = (idx & 15) * 4;
        float4 qv = *(const float4*)(qkv + (base + (size_t)qt * 64 + r) * 3072 + qc + c);
        qv.x *= 0.125f; qv.y *= 0.125f; qv.z *= 0.125f; qv.w *= 0.125f;
        *(float4*)&Qs[r][c] = qv;
    }

    float m[4], l[4], o[4][4];
#pragma unroll
    for (int i = 0; i < 4; ++i) {
        m[i] = -1e30f;
        l[i] = 0.f;
#pragma unroll
        for (int j = 0; j < 4; ++j) o[i][j] = 0.f;
    }

    for (int kt = 0; kt < Ss / 64; ++kt) {
        __syncthreads();  // prev PV reads done before overwriting K/V (also orders Q load)
#pragma unroll
        for (int rep = 0; rep < 4; ++rep) {
            int idx = rep * 256 + tid;
            int r = idx >> 4;
            int c = (idx & 15) * 4;
            const float* rowp = qkv + (base + (size_t)kt * 64 + r) * 3072;
            float4 kv = *(const float4*)(rowp + kc + c);
            Kst[c + 0][r] = kv.x;
            Kst[c + 1][r] = kv.y;
            Kst[c + 2][r] = kv.z;
            Kst[c + 3][r] = kv.w;
            *(float4*)&Vs[r][c] = *(const float4*)(rowp + vc + c);
        }
        __syncthreads();

        // scores: s[i][j] = sum_d Qs[ty*4+i][d] * Kst[d][tx*4+j]
        float s[4][4];
#pragma unroll
        for (int i = 0; i < 4; ++i)
#pragma unroll
            for (int j = 0; j < 4; ++j) s[i][j] = 0.f;

#pragma unroll
        for (int d0 = 0; d0 < HD; d0 += 4) {
            float q4[4][4], k4[4][4];
#pragma unroll
            for (int i = 0; i < 4; ++i)
                *(float4*)q4[i] = *(const float4*)&Qs[ty * 4 + i][d0];
#pragma unroll
            for (int ll = 0; ll < 4; ++ll)
                *(float4*)k4[ll] = *(const float4*)&Kst[d0 + ll][tx * 4];
#pragma unroll
            for (int i = 0; i < 4; ++i)
#pragma unroll
                for (int ll = 0; ll < 4; ++ll)
#pragma unroll
                    for (int j = 0; j < 4; ++j)
                        s[i][j] = fmaf(q4[i][ll], k4[ll][j], s[i][j]);
        }

        // online softmax (row groups = 16 consecutive lanes, shfl_xor reduce)
#pragma unroll
        for (int i = 0; i < 4; ++i) {
            float mx = fmaxf(fmaxf(s[i][0], s[i][1]), fmaxf(s[i][2], s[i][3]));
#pragma unroll
            for (int off = 1; off < 16; off <<= 1)
                mx = fmaxf(mx, __shfl_xor(mx, off, 64));
            float mn = fmaxf(m[i], mx);
            float al = expf(m[i] - mn);
            float rs = 0.f;
#pragma unroll
            for (int j = 0; j < 4; ++j) {
                s[i][j] = expf(s[i][j] - mn);
                rs += s[i][j];
            }
#pragma unroll
            for (int off = 1; off < 16; off <<= 1)
                rs += __shfl_xor(rs, off, 64);
            l[i] = l[i] * al + rs;
            m[i] = mn;
#pragma unroll
            for (int j = 0; j < 4; ++j) o[i][j] *= al;
            float4 pv;
            pv.x = s[i][0]; pv.y = s[i][1]; pv.z = s[i][2]; pv.w = s[i][3];
            *(float4*)&Ps[ty * 4 + i][tx * 4] = pv;
        }
        __syncthreads();

        // PV: o[i][j] += sum_k Ps[qi][k] * Vs[k][tx*4+j]
#pragma unroll
        for (int k4i = 0; k4i < 64; k4i += 4) {
            float p4[4][4], v4[4][4];
#pragma unroll
            for (int i = 0; i < 4; ++i)
                *(float4*)p4[i] = *(const float4*)&Ps[ty * 4 + i][k4i];
#pragma unroll
            for (int ll = 0; ll < 4; ++ll)
                *(float4*)v4[ll] = *(const float4*)&Vs[k4i + ll][tx * 4];
#pragma unroll
            for (int i = 0; i < 4; ++i)
#pragma unroll
                for (int ll = 0; ll < 4; ++ll)
#pragma unroll
                    for (int j = 0; j < 4; ++j)
                        o[i][j] = fmaf(p4[i][ll], v4[ll][j], o[i][j]);
        }
    }

    // Final: divide by l, write attn[token, h*64 + d]
#pragma unroll
    for (int i = 0; i < 4; ++i) {
        float inv = 1.f / l[i];
        float4 ov;
        ov.x = o[i][0] * inv;
        ov.y = o[i][1] * inv;
        ov.z = o[i][2] * inv;
        ov.w = o[i][3] * inv;
        size_t r = base + (size_t)qt * 64 + ty * 4 + i;
        *(float4*)(attn + r * Dd + h * 64 + tx * 4) = ov;
    }
}

// ---------------------------------------------------------------------------
// out[row] = LayerNorm(x[row] + delta[row]) * g + beta. One block per row.
// D=1024, 256 threads, 4 elements each.
// ---------------------------------------------------------------------------
__global__ __launch_bounds__(256) void ln_res(
    const float* __restrict__ xin, const float* __restrict__ delta,
    const float* __restrict__ g, const float* __restrict__ beta,
    float* __restrict__ out)
{
    __shared__ float red[8];
    const int row = blockIdx.x;
    const int tid = threadIdx.x;
    const size_t ofs = (size_t)row * Dd + tid * 4;

    float4 xv = *(const float4*)(xin + ofs);
    float4 dv = *(const float4*)(delta + ofs);
    float v0 = xv.x + dv.x, v1 = xv.y + dv.y, v2 = xv.z + dv.z, v3 = xv.w + dv.w;

    float sum = v0 + v1 + v2 + v3;
#pragma unroll
    for (int off = 1; off < 64; off <<= 1) sum += __shfl_xor(sum, off, 64);
    const int wid = tid >> 6;
    if ((tid & 63) == 0) red[wid] = sum;
    __syncthreads();
    sum = red[0] + red[1] + red[2] + red[3];
    const float mean = sum * (1.f / Dd);

    float d0 = v0 - mean, d1 = v1 - mean, d2 = v2 - mean, d3 = v3 - mean;
    float s2 = d0 * d0 + d1 * d1 + d2 * d2 + d3 * d3;
#pragma unroll
    for (int off = 1; off < 64; off <<= 1) s2 += __shfl_xor(s2, off, 64);
    if ((tid & 63) == 0) red[4 + wid] = s2;
    __syncthreads();
    s2 = red[4] + red[5] + red[6] + red[7];
    const float rstd = rsqrtf(s2 * (1.f / Dd) + 1e-5f);

    float4 gv = *(const float4*)(g + (size_t)tid * 4);
    float4 bv = *(const float4*)(beta + (size_t)tid * 4);
    float4 ov;
    ov.x = d0 * rstd * gv.x + bv.x;
    ov.y = d1 * rstd * gv.y + bv.y;
    ov.z = d2 * rstd * gv.z + bv.z;
    ov.w = d3 * rstd * gv.w + bv.w;
    *(float4*)(out + ofs) = ov;
}

// ---------------------------------------------------------------------------
// Orchestration. Workspace arena (floats), with dead-region reuse:
//   [0,            12.58M) qkv            (dead after flash)
//   [12.58M,       16.78M) attn           (dead after Wo gemm)
//   [0,             4.19M) proj           (dead after ln1)       \ reuse
//   [4.19M,         8.38M) x1             (live to the end)      | of the
//   [8.38M,        25.17M) ff1            (dead after W2 gemm)   | qkv/attn
//   [0,             4.19M) tmp2           (dead after ln2)       / regions
// Peak = 25.17M floats = 100.7 MB.
// ---------------------------------------------------------------------------
extern "C" void kernel_launch(void* const* d_in, const int* in_sizes, int n_in,
                              void* d_out, int out_size, void* d_ws, size_t ws_size,
                              hipStream_t stream)
{
    (void)in_sizes; (void)n_in; (void)out_size; (void)ws_size;
    const float* x    = (const float*)d_in[0];
    const float* Wqkv = (const float*)d_in[1];
    const float* bqkv = (const float*)d_in[2];
    const float* Wo   = (const float*)d_in[3];
    const float* bo   = (const float*)d_in[4];
    const float* W1   = (const float*)d_in[5];
    const float* b1   = (const float*)d_in[6];
    const float* W2   = (const float*)d_in[7];
    const float* b2   = (const float*)d_in[8];
    const float* g1   = (const float*)d_in[9];
    const float* be1  = (const float*)d_in[10];
    const float* g2   = (const float*)d_in[11];
    const float* be2  = (const float*)d_in[12];

    float* ws   = (float*)d_ws;
    float* qkv  = ws;                              // 12.58M floats
    float* attn = ws + (size_t)Mm * 3 * Dd;        // 4.19M
    float* proj = ws;                              // reuse (qkv dead)
    float* x1   = ws + (size_t)Mm * Dd;            // 4.19M
    float* ff1  = ws + (size_t)2 * Mm * Dd;        // 16.78M
    float* tmp2 = ws;                              // reuse (proj dead)

    dim3 blk(256);

    // 1. qkv = x @ Wqkv + bqkv                       [4096, 3072]
    gemm_bias<false><<<dim3(3 * Dd / 128, Mm / 128), blk, 0, stream>>>(
        x, Wqkv, bqkv, qkv, Mm, 3 * Dd, Dd);

    // 2. attn = flash_attention(qkv)                 [4096, 1024]
    flash_attn<<<dim3(Ss / 64, Bb * Hh), blk, 0, stream>>>(qkv, attn);

    // 3. proj = attn @ Wo + bo                       [4096, 1024]
    gemm_bias<false><<<dim3(Dd / 128, Mm / 128), blk, 0, stream>>>(
        attn, Wo, bo, proj, Mm, Dd, Dd);

    // 4. x1 = LN(x + proj; g1, be1)                  [4096, 1024]
    ln_res<<<Mm, blk, 0, stream>>>(x, proj, g1, be1, x1);

    // 5. ff1 = gelu(x1 @ W1 + b1)                    [4096, 4096]
    gemm_bias<true><<<dim3(Ff / 128, Mm / 128), blk, 0, stream>>>(
        x1, W1, b1, ff1, Mm, Ff, Dd);

    // 6. tmp2 = ff1 @ W2 + b2                        [4096, 1024]
    gemm_bias<false><<<dim3(Dd / 128, Mm / 128), blk, 0, stream>>>(
        ff1, W2, b2, tmp2, Mm, Dd, Ff);

    // 7. out = LN(x1 + tmp2; g2, be2)                [4096, 1024]
    ln_res<<<Mm, blk, 0, stream>>>(x1, tmp2, g2, be2, (float*)d_out);
}

// Round 2
// 484.579 us; speedup vs baseline: 4.6910x; 4.6910x over previous
//
#include <hip/hip_runtime.h>
#include <hip/hip_bf16.h>

typedef unsigned int u32;
typedef unsigned short u16;
typedef __attribute__((ext_vector_type(4))) float f32x4;
typedef __attribute__((ext_vector_type(8))) short s16x8;
typedef __attribute__((ext_vector_type(4))) short s16x4;

constexpr int Bb = 2, Ss = 2048, Dd = 1024, Ff = 4096, Hh = 16, HD = 64;
constexpr int Mm = Bb * Ss;  // 4096 token rows

// ---------------- helpers ----------------
__device__ __forceinline__ u16 f2bf(float f) {
    u32 u = __builtin_bit_cast(u32, f);
    u32 r = (u + 0x7FFFu + ((u >> 16) & 1u)) >> 16;   // RNE
    return (u16)r;
}
__device__ __forceinline__ float bf2f(u16 b) {
    u32 u = ((u32)b) << 16;
    return __builtin_bit_cast(float, u);
}
__device__ __forceinline__ float gelu_exact(float x) {
    return 0.5f * x * (1.0f + erff(x * 0.70710678118654752f));
}
// async global->LDS, 16B per lane. lds base must be wave-uniform (HW writes
// base + lane*16); global address is per-lane.
__device__ __forceinline__ void gload16(const void* g, void* l) {
    __builtin_amdgcn_global_load_lds(
        (const __attribute__((address_space(1))) u32*)g,
        (__attribute__((address_space(3))) u32*)l, 16, 0, 0);
}

// ---------------------------------------------------------------------------
// bf16 MFMA GEMM: C[M,N] = A[M,K] @ Bt[N,K]^T + bias, OUT in {f32,bf16}, opt GELU.
// 128x128 tile, BK=32, 256 thr (4 waves, 2x2 of 64x64), 16x16x32 MFMA.
// LDS tiles [128 rows][32 k] bf16 (64B rows, 4x16B chunks). Swizzle (rule #21):
// linear LDS dest via global_load_lds; SOURCE chunk = lin ^ swz(r); READ chunk
// = need ^ swz(r); swz(r) = (r ^ (r>>2)) & 3  -> 2-way bank aliasing (free).
// ---------------------------------------------------------------------------
template <bool OUT_BF16, bool GELU>
__global__ __launch_bounds__(256) void gemm_tn(
    const u16* __restrict__ A, const u16* __restrict__ Bt,
    const float* __restrict__ bias, void* __restrict__ C,
    int M, int N, int K)
{
    __shared__ __align__(16) u16 As[128 * 32];
    __shared__ __align__(16) u16 Bs[128 * 32];
    const int tid = threadIdx.x;
    const int l = tid & 63;
    const int w = tid >> 6;
    const int wr = w >> 1, wc = w & 1;
    const int brow = blockIdx.y * 128, bcol = blockIdx.x * 128;

    f32x4 acc[4][4];
#pragma unroll
    for (int i = 0; i < 4; ++i)
#pragma unroll
        for (int j = 0; j < 4; ++j) acc[i][j] = (f32x4){0.f, 0.f, 0.f, 0.f};

    // staging: per wave 2 issues per matrix, 16 rows each (4 lanes/row x 16B)
    const int sr0 = (w * 2 + 0) * 16 + (l >> 2);
    const int sr1 = (w * 2 + 1) * 16 + (l >> 2);
    const int clin = l & 3;
    const int cs0 = clin ^ ((sr0 ^ (sr0 >> 2)) & 3);
    const int cs1 = clin ^ ((sr1 ^ (sr1 >> 2)) & 3);
    const u16* gA0 = A + (size_t)(brow + sr0) * K + cs0 * 8;
    const u16* gA1 = A + (size_t)(brow + sr1) * K + cs1 * 8;
    const u16* gB0 = Bt + (size_t)(bcol + sr0) * K + cs0 * 8;
    const u16* gB1 = Bt + (size_t)(bcol + sr1) * K + cs1 * 8;
    u16* lA0 = As + (w * 2 + 0) * 512;
    u16* lA1 = As + (w * 2 + 1) * 512;
    u16* lB0 = Bs + (w * 2 + 0) * 512;
    u16* lB1 = Bs + (w * 2 + 1) * 512;

    // fragment read offsets (elements): row r, chunk (l>>4)^swz(r)
    int aof[4], bof[4];
#pragma unroll
    for (int i = 0; i < 4; ++i) {
        int r = wr * 64 + i * 16 + (l & 15);
        aof[i] = r * 32 + (((l >> 4) ^ ((r ^ (r >> 2)) & 3)) * 8);
        int rn = wc * 64 + i * 16 + (l & 15);
        bof[i] = rn * 32 + (((l >> 4) ^ ((rn ^ (rn >> 2)) & 3)) * 8);
    }

    for (int k0 = 0; k0 < K; k0 += 32) {
        __syncthreads();
        gload16(gA0 + k0, lA0);
        gload16(gA1 + k0, lA1);
        gload16(gB0 + k0, lB0);
        gload16(gB1 + k0, lB1);
        __syncthreads();

        s16x8 af[4], bfr[4];
#pragma unroll
        for (int i = 0; i < 4; ++i) af[i] = *(const s16x8*)(As + aof[i]);
#pragma unroll
        for (int i = 0; i < 4; ++i) bfr[i] = *(const s16x8*)(Bs + bof[i]);
#pragma unroll
        for (int mi = 0; mi < 4; ++mi)
#pragma unroll
            for (int ni = 0; ni < 4; ++ni)
                acc[mi][ni] = __builtin_amdgcn_mfma_f32_16x16x32_bf16(
                    af[mi], bfr[ni], acc[mi][ni], 0, 0, 0);
    }

    // epilogue: C/D layout col = lane&15, row = (lane>>4)*4 + reg  [m89]
    float bc[4];
#pragma unroll
    for (int ni = 0; ni < 4; ++ni)
        bc[ni] = bias[bcol + wc * 64 + ni * 16 + (l & 15)];
#pragma unroll
    for (int mi = 0; mi < 4; ++mi) {
        const int row0 = brow + wr * 64 + mi * 16 + (l >> 4) * 4;
#pragma unroll
        for (int ni = 0; ni < 4; ++ni) {
            const int col = bcol + wc * 64 + ni * 16 + (l & 15);
#pragma unroll
            for (int rg = 0; rg < 4; ++rg) {
                float v = acc[mi][ni][rg] + bc[ni];
                if (GELU) v = gelu_exact(v);
                if (OUT_BF16)
                    ((u16*)C)[(size_t)(row0 + rg) * N + col] = f2bf(v);
                else
                    ((float*)C)[(size_t)(row0 + rg) * N + col] = v;
            }
        }
    }
}

// ---------------------------------------------------------------------------
// Flash attention, bf16 MFMA. qkv[token][3072] (head h: q|k|v @ h*192).
// Vtg[(bh*64+d)][s] pre-transposed V. Block = (qtile of 128) x (b,h); 4 waves,
// wave w owns q rows w*32..+32 (2 m-frags). K-tiles of 64. 128B LDS rows ->
// swizzle chunk ^= (row&7) (2-way, free). P per wave in swizzled LDS.
// ---------------------------------------------------------------------------
__global__ __launch_bounds__(256) void attn_mfma(
    const u16* __restrict__ qkv, const u16* __restrict__ Vtg,
    u16* __restrict__ attn)
{
    __shared__ __align__(16) u16 Ks[64 * 64];    // [key][d]
    __shared__ __align__(16) u16 Vs[64 * 64];    // [d][key]
    __shared__ __align__(16) u16 Ps[4 * 32 * 64];// per-wave [32 q][64 key]
    const int tid = threadIdx.x, l = tid & 63, w = tid >> 6;
    const int qt = blockIdx.x;           // 0..15
    const int bh = blockIdx.y;           // 0..31
    const int b = bh >> 4, h = bh & 15;
    const size_t tokbase = (size_t)b * Ss;
    const int qc = h * 192, kc = qc + 64;

    // Q fragments hoisted to registers, scaled by 1/8 (exact in bf16)
    s16x8 qf[2][2];
#pragma unroll
    for (int mi = 0; mi < 2; ++mi) {
        const int row = qt * 128 + w * 32 + mi * 16 + (l & 15);
        const u16* qp = qkv + (tokbase + row) * 3072 + qc + (l >> 4) * 8;
#pragma unroll
        for (int kh = 0; kh < 2; ++kh) {
            s16x8 v = *(const s16x8*)(qp + kh * 32);
#pragma unroll
            for (int j = 0; j < 8; ++j)
                v[j] = (short)f2bf(bf2f((u16)v[j]) * 0.125f);
            qf[mi][kh] = v;
        }
    }

    float mrow[2][4], lrow[2][4];
    f32x4 o[2][4];
#pragma unroll
    for (int mi = 0; mi < 2; ++mi)
#pragma unroll
        for (int rg = 0; rg < 4; ++rg) { mrow[mi][rg] = -1e30f; lrow[mi][rg] = 0.f; }
#pragma unroll
    for (int mi = 0; mi < 2; ++mi)
#pragma unroll
        for (int ni = 0; ni < 4; ++ni) o[mi][ni] = (f32x4){0.f, 0.f, 0.f, 0.f};

    // staging (per wave 2 issues per tile, 8 rows of 128B per issue)
    const int sr0 = (w * 2 + 0) * 8 + (l >> 3);
    const int sr1 = (w * 2 + 1) * 8 + (l >> 3);
    const int cl3 = l & 7;
    const int cv0 = cl3 ^ (sr0 & 7);
    const int cv1 = cl3 ^ (sr1 & 7);
    u16* lK0 = Ks + (w * 2 + 0) * 512;  u16* lK1 = Ks + (w * 2 + 1) * 512;
    u16* lV0 = Vs + (w * 2 + 0) * 512;  u16* lV1 = Vs + (w * 2 + 1) * 512;
    u16* pw = Ps + w * 2048;

    for (int kt = 0; kt < Ss / 64; ++kt) {
        __syncthreads();
        const size_t krow = tokbase + kt * 64;
        gload16(qkv + (krow + sr0) * 3072 + kc + cv0 * 8, lK0);
        gload16(qkv + (krow + sr1) * 3072 + kc + cv1 * 8, lK1);
        gload16(Vtg + (size_t)(bh * 64 + sr0) * Ss + kt * 64 + cv0 * 8, lV0);
        gload16(Vtg + (size_t)(bh * 64 + sr1) * Ss + kt * 64 + cv1 * 8, lV1);
        __syncthreads();

        // S = Q K^T
        f32x4 s[2][4];
#pragma unroll
        for (int mi = 0; mi < 2; ++mi)
#pragma unroll
            for (int ni = 0; ni < 4; ++ni) s[mi][ni] = (f32x4){0.f, 0.f, 0.f, 0.f};
#pragma unroll
        for (int kh = 0; kh < 2; ++kh)
#pragma unroll
            for (int ni = 0; ni < 4; ++ni) {
                const int key = ni * 16 + (l & 15);
                const int ch = (kh * 4 + (l >> 4)) ^ (key & 7);
                s16x8 kf = *(const s16x8*)(Ks + key * 64 + ch * 8);
#pragma unroll
                for (int mi = 0; mi < 2; ++mi)
                    s[mi][ni] = __builtin_amdgcn_mfma_f32_16x16x32_bf16(
                        qf[mi][kh], kf, s[mi][ni], 0, 0, 0);
            }

        // online softmax; write P (bf16) into swizzled wave-private LDS
#pragma unroll
        for (int mi = 0; mi < 2; ++mi)
#pragma unroll
            for (int rg = 0; rg < 4; ++rg) {
                float s0 = s[mi][0][rg], s1 = s[mi][1][rg];
                float s2 = s[mi][2][rg], s3 = s[mi][3][rg];
                float mx = fmaxf(fmaxf(s0, s1), fmaxf(s2, s3));
#pragma unroll
                for (int off = 1; off < 16; off <<= 1)
                    mx = fmaxf(mx, __shfl_xor(mx, off, 64));
                const float mnew = fmaxf(mrow[mi][rg], mx);
                const float alpha = __expf(mrow[mi][rg] - mnew);
                float p0 = __expf(s0 - mnew), p1 = __expf(s1 - mnew);
                float p2 = __expf(s2 - mnew), p3 = __expf(s3 - mnew);
                float rs = p0 + p1 + p2 + p3;
#pragma unroll
                for (int off = 1; off < 16; off <<= 1)
                    rs += __shfl_xor(rs, off, 64);
                lrow[mi][rg] = lrow[mi][rg] * alpha + rs;
                mrow[mi][rg] = mnew;
#pragma unroll
                for (int ni = 0; ni < 4; ++ni) o[mi][ni][rg] *= alpha;
                const int rq = mi * 16 + (l >> 4) * 4 + rg;
                const int kb = l & 15;
                pw[rq * 64 + (((0 * 16 + kb) >> 3) ^ (rq & 7)) * 8 + (kb & 7)] = f2bf(p0);
                pw[rq * 64 + (((1 * 16 + kb) >> 3) ^ (rq & 7)) * 8 + (kb & 7)] = f2bf(p1);
                pw[rq * 64 + (((2 * 16 + kb) >> 3) ^ (rq & 7)) * 8 + (kb & 7)] = f2bf(p2);
                pw[rq * 64 + (((3 * 16 + kb) >> 3) ^ (rq & 7)) * 8 + (kb & 7)] = f2bf(p3);
            }
        asm volatile("s_waitcnt lgkmcnt(0)" ::: "memory");
        __builtin_amdgcn_sched_barrier(0);

        // O += P V
#pragma unroll
        for (int kh = 0; kh < 2; ++kh) {
            s16x8 pf[2];
#pragma unroll
            for (int mi = 0; mi < 2; ++mi) {
                const int rq = mi * 16 + (l & 15);
                const int ch = (kh * 4 + (l >> 4)) ^ (rq & 7);
                pf[mi] = *(const s16x8*)(pw + rq * 64 + ch * 8);
            }
#pragma unroll
            for (int ni = 0; ni < 4; ++ni) {
                const int d = ni * 16 + (l & 15);
                const int ch = (kh * 4 + (l >> 4)) ^ (d & 7);
                s16x8 vf = *(const s16x8*)(Vs + d * 64 + ch * 8);
#pragma unroll
                for (int mi = 0; mi < 2; ++mi)
                    o[mi][ni] = __builtin_amdgcn_mfma_f32_16x16x32_bf16(
                        pf[mi], vf, o[mi][ni], 0, 0, 0);
            }
        }
    }

    // normalize + store bf16
#pragma unroll
    for (int mi = 0; mi < 2; ++mi)
#pragma unroll
        for (int rg = 0; rg < 4; ++rg) {
            const float inv = 1.f / lrow[mi][rg];
            const size_t tok = tokbase + qt * 128 + w * 32 + mi * 16 + (l >> 4) * 4 + rg;
#pragma unroll
            for (int ni = 0; ni < 4; ++ni)
                attn[tok * Dd + h * 64 + ni * 16 + (l & 15)] =
                    f2bf(o[mi][ni][rg] * inv);
        }
}

// ---------------------------------------------------------------------------
// fp32 -> bf16 elementwise convert (x -> xb), 4 elems/thread
// ---------------------------------------------------------------------------
__global__ __launch_bounds__(256) void conv_bf16(const float* __restrict__ in,
                                                 u16* __restrict__ out) {
    const int i = blockIdx.x * 256 + threadIdx.x;
    float4 v = ((const float4*)in)[i];
    s16x4 o;
    o[0] = (short)f2bf(v.x); o[1] = (short)f2bf(v.y);
    o[2] = (short)f2bf(v.z); o[3] = (short)f2bf(v.w);
    ((s16x4*)out)[i] = o;
}

// ---------------------------------------------------------------------------
// W[K][N] f32 -> Wt[N][K] bf16 (64x64 LDS tile, u32-per-elem to dodge
// alignment/bank pain; 2-way write aliasing with pad 65)
// ---------------------------------------------------------------------------
__global__ __launch_bounds__(256) void transpose_w(const float* __restrict__ W,
                                                   u16* __restrict__ Wt,
                                                   int K, int N) {
    __shared__ u32 tile[64][65];
    const int n0 = blockIdx.x * 64, k0 = blockIdx.y * 64;
    const int t = threadIdx.x;
#pragma unroll
    for (int i = 0; i < 4; ++i) {
        const int flat = i * 256 + t;
        const int kr = flat >> 4, c4 = (flat & 15) * 4;
        float4 v = *(const float4*)(W + (size_t)(k0 + kr) * N + n0 + c4);
        tile[c4 + 0][kr] = (u32)f2bf(v.x);
        tile[c4 + 1][kr] = (u32)f2bf(v.y);
        tile[c4 + 2][kr] = (u32)f2bf(v.z);
        tile[c4 + 3][kr] = (u32)f2bf(v.w);
    }
    __syncthreads();
#pragma unroll
    for (int i = 0; i < 4; ++i) {
        const int flat = i * 256 + t;
        const int nr = flat >> 4, k4 = (flat & 15) * 4;
        s16x4 o;
#pragma unroll
        for (int j = 0; j < 4; ++j) o[j] = (short)tile[nr][k4 + j];
        *(s16x4*)(Wt + (size_t)(n0 + nr) * K + k0 + k4) = o;
    }
}

// ---------------------------------------------------------------------------
// V columns of qkv (bf16) -> Vtg[(bh*64+d)][s] (64s x 64d tiles)
// ---------------------------------------------------------------------------
__global__ __launch_bounds__(256) void vtrans(const u16* __restrict__ qkv,
                                              u16* __restrict__ Vtg) {
    __shared__ u32 tile[64][65];
    const int st = blockIdx.x;          // s-tile 0..31
    const int bh = blockIdx.y;          // 0..31
    const int b = bh >> 4, h = bh & 15;
    const int t = threadIdx.x;
    const int vc = h * 192 + 128;
#pragma unroll
    for (int i = 0; i < 4; ++i) {
        const int flat = i * 256 + t;
        const int s = flat >> 4, c4 = (flat & 15) * 4;
        s16x4 v = *(const s16x4*)(qkv + ((size_t)b * Ss + st * 64 + s) * 3072 + vc + c4);
#pragma unroll
        for (int j = 0; j < 4; ++j) tile[c4 + j][s] = (u32)(u16)v[j];
    }
    __syncthreads();
#pragma unroll
    for (int i = 0; i < 4; ++i) {
        const int flat = i * 256 + t;
        const int d = flat >> 4, s4 = (flat & 15) * 4;
        s16x4 o;
#pragma unroll
        for (int j = 0; j < 4; ++j) o[j] = (short)tile[d][s4 + j];
        *(s16x4*)(Vtg + ((size_t)bh * 64 + d) * Ss + st * 64 + s4) = o;
    }
}

// ---------------------------------------------------------------------------
// out = LN(x + delta) * g + beta (f32); optionally also bf16 copy.
// ---------------------------------------------------------------------------
template <bool WB>
__global__ __launch_bounds__(256) void ln_res(
    const float* __restrict__ xin, const float* __restrict__ delta,
    const float* __restrict__ g, const float* __restrict__ beta,
    float* __restrict__ out, u16* __restrict__ outb)
{
    __shared__ float red[8];
    const int row = blockIdx.x;
    const int tid = threadIdx.x;
    const size_t ofs = (size_t)row * Dd + tid * 4;

    float4 xv = *(const float4*)(xin + ofs);
    float4 dv = *(const float4*)(delta + ofs);
    float v0 = xv.x + dv.x, v1 = xv.y + dv.y, v2 = xv.z + dv.z, v3 = xv.w + dv.w;

    float sum = v0 + v1 + v2 + v3;
#pragma unroll
    for (int off = 1; off < 64; off <<= 1) sum += __shfl_xor(sum, off, 64);
    const int wid = tid >> 6;
    if ((tid & 63) == 0) red[wid] = sum;
    __syncthreads();
    sum = red[0] + red[1] + red[2] + red[3];
    const float mean = sum * (1.f / Dd);

    float d0 = v0 - mean, d1 = v1 - mean, d2 = v2 - mean, d3 = v3 - mean;
    float s2 = d0 * d0 + d1 * d1 + d2 * d2 + d3 * d3;
#pragma unroll
    for (int off = 1; off < 64; off <<= 1) s2 += __shfl_xor(s2, off, 64);
    if ((tid & 63) == 0) red[4 + wid] = s2;
    __syncthreads();
    s2 = red[4] + red[5] + red[6] + red[7];
    const float rstd = rsqrtf(s2 * (1.f / Dd) + 1e-5f);

    float4 gv = *(const float4*)(g + (size_t)tid * 4);
    float4 bv = *(const float4*)(beta + (size_t)tid * 4);
    float4 ov;
    ov.x = d0 * rstd * gv.x + bv.x;
    ov.y = d1 * rstd * gv.y + bv.y;
    ov.z = d2 * rstd * gv.z + bv.z;
    ov.w = d3 * rstd * gv.w + bv.w;
    *(float4*)(out + ofs) = ov;
    if (WB) {
        s16x4 ob;
        ob[0] = (short)f2bf(ov.x); ob[1] = (short)f2bf(ov.y);
        ob[2] = (short)f2bf(ov.z); ob[3] = (short)f2bf(ov.w);
        *(s16x4*)(outb + ofs) = ob;
    }
}

// ---------------------------------------------------------------------------
// Workspace arena (byte offsets, overlap-checked against liveness):
//  x1f    @0          16.78M  (LN1 -> LN2)
//  x1b    @16777216    8.39M  (LN1 -> GEMM3)
//  W1T    @25165824    8.39M  (-> GEMM3)
//  W2T    @33554432    8.39M  (-> GEMM4)
//  xb     @41943040    8.39M  (-> GEMM1)      } overlapped later by ff1
//  WqkvT  @50331648    6.29M  (-> GEMM1)      }
//  WoT    @56623104    2.10M  (-> GEMM2)      }
//  qkv    @58720256   25.17M  (-> vtrans/attn)} head overlapped by ff1/proj
//  Vtg    @83886080    8.39M  (-> attn)        overlapped later by tmp2
//  attnB  @92274688    8.39M  (-> GEMM2)
//  proj   @58720256   16.78M  f32 (GEMM2 -> LN1; qkv dead by then)
//  ff1    @41943040   33.55M  (GEMM3 -> GEMM4; xb/WqkvT/WoT/qkv-head dead)
//  tmp2   @75497472   16.78M  f32 (GEMM4 -> LN2; qkv-tail/Vtg dead)
// peak 100,663,296 B
// ---------------------------------------------------------------------------
extern "C" void kernel_launch(void* const* d_in, const int* in_sizes, int n_in,
                              void* d_out, int out_size, void* d_ws, size_t ws_size,
                              hipStream_t stream)
{
    (void)in_sizes; (void)n_in; (void)out_size; (void)ws_size;
    const float* x    = (const float*)d_in[0];
    const float* Wqkv = (const float*)d_in[1];
    const float* bqkv = (const float*)d_in[2];
    const float* Wo   = (const float*)d_in[3];
    const float* bo   = (const float*)d_in[4];
    const float* W1   = (const float*)d_in[5];
    const float* b1   = (const float*)d_in[6];
    const float* W2   = (const float*)d_in[7];
    const float* b2   = (const float*)d_in[8];
    const float* g1   = (const float*)d_in[9];
    const float* be1  = (const float*)d_in[10];
    const float* g2   = (const float*)d_in[11];
    const float* be2  = (const float*)d_in[12];

    char* ws = (char*)d_ws;
    float* x1f   = (float*)(ws + 0);
    u16*   x1b   = (u16*)(ws + 16777216);
    u16*   W1T   = (u16*)(ws + 25165824);
    u16*   W2T   = (u16*)(ws + 33554432);
    u16*   xb    = (u16*)(ws + 41943040);
    u16*   WqkvT = (u16*)(ws + 50331648);
    u16*   WoT   = (u16*)(ws + 56623104);
    u16*   qkv   = (u16*)(ws + 58720256);
    u16*   Vtg   = (u16*)(ws + 83886080);
    u16*   attnB = (u16*)(ws + 92274688);
    float* proj  = (float*)(ws + 58720256);
    u16*   ff1   = (u16*)(ws + 41943040);
    float* tmp2  = (float*)(ws + 75497472);

    dim3 blk(256);

    // 0. converts / transposes
    conv_bf16<<<Mm * Dd / 4 / 256, blk, 0, stream>>>(x, xb);
    transpose_w<<<dim3(3 * Dd / 64, Dd / 64), blk, 0, stream>>>(Wqkv, WqkvT, Dd, 3 * Dd);
    transpose_w<<<dim3(Dd / 64, Dd / 64), blk, 0, stream>>>(Wo, WoT, Dd, Dd);
    transpose_w<<<dim3(Ff / 64, Dd / 64), blk, 0, stream>>>(W1, W1T, Dd, Ff);
    transpose_w<<<dim3(Dd / 64, Ff / 64), blk, 0, stream>>>(W2, W2T, Ff, Dd);

    // 1. qkv = xb @ WqkvT^T + bqkv          [4096,3072] bf16
    gemm_tn<true, false><<<dim3(3 * Dd / 128, Mm / 128), blk, 0, stream>>>(
        xb, WqkvT, bqkv, qkv, Mm, 3 * Dd, Dd);

    // 2. Vtg = transpose(V part of qkv)
    vtrans<<<dim3(Ss / 64, Bb * Hh), blk, 0, stream>>>(qkv, Vtg);

    // 3. attnB = flash_attention(qkv, Vtg)  [4096,1024] bf16
    attn_mfma<<<dim3(Ss / 128, Bb * Hh), blk, 0, stream>>>(qkv, Vtg, attnB);

    // 4. proj = attnB @ WoT^T + bo          [4096,1024] f32
    gemm_tn<false, false><<<dim3(Dd / 128, Mm / 128), blk, 0, stream>>>(
        attnB, WoT, bo, proj, Mm, Dd, Dd);

    // 5. x1f/x1b = LN(x + proj)
    ln_res<true><<<Mm, blk, 0, stream>>>(x, proj, g1, be1, x1f, x1b);

    // 6. ff1 = gelu(x1b @ W1T^T + b1)       [4096,4096] bf16
    gemm_tn<true, true><<<dim3(Ff / 128, Mm / 128), blk, 0, stream>>>(
        x1b, W1T, b1, ff1, Mm, Ff, Dd);

    // 7. tmp2 = ff1 @ W2T^T + b2            [4096,1024] f32
    gemm_tn<false, false><<<dim3(Dd / 128, Mm / 128), blk, 0, stream>>>(
        ff1, W2T, b2, tmp2, Mm, Dd, Ff);

    // 8. out = LN(x1f + tmp2)
    ln_res<false><<<Mm, blk, 0, stream>>>(x1f, tmp2, g2, be2, (float*)d_out, nullptr);
}

// Round 4
// 433.136 us; speedup vs baseline: 5.2481x; 1.1188x over previous
//
#include <hip/hip_runtime.h>
#include <hip/hip_bf16.h>

typedef unsigned int u32;
typedef unsigned short u16;
typedef __attribute__((ext_vector_type(4))) float f32x4;
typedef __attribute__((ext_vector_type(8))) short s16x8;
typedef __attribute__((ext_vector_type(4))) short s16x4;

constexpr int Bb = 2, Ss = 2048, Dd = 1024, Ff = 4096, Hh = 16, HD = 64;
constexpr int Mm = Bb * Ss;  // 4096 token rows

// ---------------- helpers ----------------
__device__ __forceinline__ u16 f2bf(float f) {
    u32 u = __builtin_bit_cast(u32, f);
    u32 r = (u + 0x7FFFu + ((u >> 16) & 1u)) >> 16;   // RNE
    return (u16)r;
}
__device__ __forceinline__ float bf2f(u16 b) {
    u32 u = ((u32)b) << 16;
    return __builtin_bit_cast(float, u);
}
__device__ __forceinline__ float gelu_exact(float x) {
    return 0.5f * x * (1.0f + erff(x * 0.70710678118654752f));
}
// async global->LDS, 16B/lane. LDS dest wave-uniform (HW adds lane*16);
// global source per-lane.
__device__ __forceinline__ void gload16(const void* g, void* l) {
    __builtin_amdgcn_global_load_lds(
        (const __attribute__((address_space(1))) u32*)g,
        (__attribute__((address_space(3))) u32*)l, 16, 0, 0);
}

// ---------------------------------------------------------------------------
// Pipelined bf16 MFMA GEMM: C = A[M,K] @ Bt[N,K]^T + bias (opt GELU).
// BK=32, triple-buffered LDS, counted vmcnt(4) (T4), chunk-XOR swizzle (T2),
// setprio around MFMA (T5). Tile t lives in buf t%3; iteration t stages tile
// t+2 into buf (t+2)%3 (never the buffer being read -> race-free); the
// boundary vmcnt(4)+s_barrier guarantees tile t+1 landed in ALL waves while
// tile t+2's 4 loads/wave stay in flight.
// Swizzle: LDS row r (64B = 4 chunks of 16B), logical chunk c stored at
// c ^ swz(r), swz(r) = (r ^ (r>>2)) & 3. Verified 0 bank conflicts (round 2).
// ---------------------------------------------------------------------------
template <int BM, int BN, int WM, int WN, bool OUT_BF16, bool GELU>
__global__ __launch_bounds__(WM * WN * 64, (WM * WN == 8) ? 2 : 3)
void gemm_pipe(const u16* __restrict__ A, const u16* __restrict__ Bt,
               const float* __restrict__ bias, void* __restrict__ C,
               int M, int N, int K)
{
    constexpr int NWAVE = WM * WN;
    constexpr int THREADS = NWAVE * 64;
    constexpr int MREP = BM / (WM * 16);
    constexpr int NREP = BN / (WN * 16);
    constexpr int ATILE = BM * 32;      // u16 elements per A tile
    constexpr int BTILE = BN * 32;
    constexpr int STEP = ATILE + BTILE;
    __shared__ __align__(16) u16 lds[3 * STEP];

    const int tid = threadIdx.x;
    const int l = tid & 63;
    const int w = tid >> 6;
    const int wr = w / WN, wc = w % WN;
    const int brow = blockIdx.y * BM, bcol = blockIdx.x * BN;
    const int nt = K / 32;

    f32x4 acc[MREP][NREP];
#pragma unroll
    for (int i = 0; i < MREP; ++i)
#pragma unroll
        for (int j = 0; j < NREP; ++j) acc[i][j] = (f32x4){0.f, 0.f, 0.f, 0.f};

    // staging: 2 issues per matrix; issue i: flat = i*THREADS+tid,
    // row = flat>>2, linear chunk = flat&3, logical = lin ^ swz(row).
    const u16* gA[2]; const u16* gB[2];
#pragma unroll
    for (int i = 0; i < 2; ++i) {
        const int flat = i * THREADS + tid;
        const int r = flat >> 2;
        const int lc = (flat & 3) ^ ((r ^ (r >> 2)) & 3);
        gA[i] = A + (size_t)(brow + r) * K + lc * 8;
        gB[i] = Bt + (size_t)(bcol + r) * K + lc * 8;
    }

    // fragment read offsets (u16 elements within a tile)
    int aoff[MREP], boff[NREP];
#pragma unroll
    for (int mi = 0; mi < MREP; ++mi) {
        const int r = wr * (MREP * 16) + mi * 16 + (l & 15);
        aoff[mi] = r * 32 + (((l >> 4) ^ ((r ^ (r >> 2)) & 3)) * 8);
    }
#pragma unroll
    for (int ni = 0; ni < NREP; ++ni) {
        const int r = wc * (NREP * 16) + ni * 16 + (l & 15);
        boff[ni] = r * 32 + (((l >> 4) ^ ((r ^ (r >> 2)) & 3)) * 8);
    }

    auto stage = [&](int s, int t) {
        u16* base = lds + s * STEP;
#pragma unroll
        for (int i = 0; i < 2; ++i)
            gload16(gA[i] + t * 32, base + i * THREADS * 8 + w * 512);
#pragma unroll
        for (int i = 0; i < 2; ++i)
            gload16(gB[i] + t * 32, base + ATILE + i * THREADS * 8 + w * 512);
    };

    // prologue: tiles 0,1 -> bufs 0,1; wait tile 0 (tile 1's 4 in flight)
    stage(0, 0);
    stage(1, 1);
    asm volatile("s_waitcnt vmcnt(4)" ::: "memory");
    __builtin_amdgcn_s_barrier();

    int cur = 0;
    for (int t = 0; t < nt; ++t) {
        if (t + 2 < nt) stage((cur + 2 >= 3) ? cur - 1 : cur + 2, t + 2);

        const u16* Ab = lds + cur * STEP;
        const u16* Bbs = Ab + ATILE;
        s16x8 af[MREP], bfr[NREP];
#pragma unroll
        for (int mi = 0; mi < MREP; ++mi) af[mi] = *(const s16x8*)(Ab + aoff[mi]);
#pragma unroll
        for (int ni = 0; ni < NREP; ++ni) bfr[ni] = *(const s16x8*)(Bbs + boff[ni]);

        __builtin_amdgcn_s_setprio(1);
#pragma unroll
        for (int mi = 0; mi < MREP; ++mi)
#pragma unroll
            for (int ni = 0; ni < NREP; ++ni)
                acc[mi][ni] = __builtin_amdgcn_mfma_f32_16x16x32_bf16(
                    af[mi], bfr[ni], acc[mi][ni], 0, 0, 0);
        __builtin_amdgcn_s_setprio(0);

        if (t + 1 < nt) {
            if (t + 2 < nt) {
                asm volatile("s_waitcnt vmcnt(4)" ::: "memory");  // t+1 landed
            } else {
                asm volatile("s_waitcnt vmcnt(0)" ::: "memory");  // drain
            }
            __builtin_amdgcn_s_barrier();
        }
        cur = (cur + 1 >= 3) ? 0 : cur + 1;
    }

    // epilogue: C/D layout col = lane&15, row = (lane>>4)*4 + reg  [m89]
    asm volatile("" ::: "memory");
    float bc[NREP];
#pragma unroll
    for (int ni = 0; ni < NREP; ++ni)
        bc[ni] = bias[bcol + wc * (NREP * 16) + ni * 16 + (l & 15)];
#pragma unroll
    for (int mi = 0; mi < MREP; ++mi) {
        const int row0 = brow + wr * (MREP * 16) + mi * 16 + (l >> 4) * 4;
#pragma unroll
        for (int ni = 0; ni < NREP; ++ni) {
            const int col = bcol + wc * (NREP * 16) + ni * 16 + (l & 15);
#pragma unroll
            for (int rg = 0; rg < 4; ++rg) {
                float v = acc[mi][ni][rg] + bc[ni];
                if (GELU) v = gelu_exact(v);
                if (OUT_BF16)
                    ((u16*)C)[(size_t)(row0 + rg) * N + col] = f2bf(v);
                else
                    ((float*)C)[(size_t)(row0 + rg) * N + col] = v;
            }
        }
    }
}

// ---------------------------------------------------------------------------
// Flash attention, bf16 MFMA. qkv[token][3072] (head h: q|k|v @ h*192).
// Vtg[(bh*64+d)][s] pre-transposed V. Q-tile 64 rows -> grid 32x32 = 1024
// blocks (4 blocks/CU). 4 waves, wave w owns q rows w*16..+16 (1 m-frag).
// K/V double-buffered with 2-phase prefetch (issue next tile before compute;
// __syncthreads drains). 128B LDS rows -> chunk ^= (row&7) swizzle (0-conflict
// measured). P per wave in swizzled LDS.
// ---------------------------------------------------------------------------
__global__ __launch_bounds__(256, 4) void attn_mfma(
    const u16* __restrict__ qkv, const u16* __restrict__ Vtg,
    u16* __restrict__ attn)
{
    __shared__ __align__(16) u16 Ks[2][64 * 64];   // [key][d]
    __shared__ __align__(16) u16 Vs[2][64 * 64];   // [d][key]
    __shared__ __align__(16) u16 Ps[4][16 * 64];   // per-wave [16 q][64 key]
    const int tid = threadIdx.x, l = tid & 63, w = tid >> 6;
    const int qt = blockIdx.x;           // 0..31
    const int bh = blockIdx.y;           // 0..31
    const int b = bh >> 4, h = bh & 15;
    const size_t tokbase = (size_t)b * Ss;
    const int qc = h * 192, kc = qc + 64;

    // Q fragments in registers, scaled by 1/8 (exact in bf16)
    s16x8 qf[2];
    {
        const int row = qt * 64 + w * 16 + (l & 15);
        const u16* qp = qkv + (tokbase + row) * 3072 + qc + (l >> 4) * 8;
#pragma unroll
        for (int kh = 0; kh < 2; ++kh) {
            s16x8 v = *(const s16x8*)(qp + kh * 32);
#pragma unroll
            for (int j = 0; j < 8; ++j)
                v[j] = (short)f2bf(bf2f((u16)v[j]) * 0.125f);
            qf[kh] = v;
        }
    }

    float mrow[4], lrow[4];
    f32x4 o[4];
#pragma unroll
    for (int rg = 0; rg < 4; ++rg) { mrow[rg] = -1e30f; lrow[rg] = 0.f; }
#pragma unroll
    for (int ni = 0; ni < 4; ++ni) o[ni] = (f32x4){0.f, 0.f, 0.f, 0.f};

    // staging: issue i covers rows i*32 + (flat>>3); linear chunk flat&7,
    // logical = lin ^ (row & 7).
    int srow[2], slc[2];
#pragma unroll
    for (int i = 0; i < 2; ++i) {
        const int flat = i * 256 + tid;
        srow[i] = flat >> 3;
        slc[i] = (flat & 7) ^ (srow[i] & 7);
    }
    u16* pw = Ps[w];

    auto stageKV = [&](int s, int kt) {
        const size_t krow = tokbase + kt * 64;
#pragma unroll
        for (int i = 0; i < 2; ++i)
            gload16(qkv + (krow + srow[i]) * 3072 + kc + slc[i] * 8,
                    Ks[s] + i * 2048 + w * 512);
#pragma unroll
        for (int i = 0; i < 2; ++i)
            gload16(Vtg + (size_t)(bh * 64 + srow[i]) * Ss + kt * 64 + slc[i] * 8,
                    Vs[s] + i * 2048 + w * 512);
    };

    stageKV(0, 0);
    __syncthreads();

    for (int kt = 0; kt < Ss / 64; ++kt) {
        const int cur = kt & 1;
        if (kt + 1 < Ss / 64) stageKV(cur ^ 1, kt + 1);

        // S = Q K^T  (8 MFMA)
        f32x4 s[4];
#pragma unroll
        for (int ni = 0; ni < 4; ++ni) s[ni] = (f32x4){0.f, 0.f, 0.f, 0.f};
#pragma unroll
        for (int kh = 0; kh < 2; ++kh)
#pragma unroll
            for (int ni = 0; ni < 4; ++ni) {
                const int key = ni * 16 + (l & 15);
                const int ch = (kh * 4 + (l >> 4)) ^ (key & 7);
                s16x8 kf = *(const s16x8*)(Ks[cur] + key * 64 + ch * 8);
                s[ni] = __builtin_amdgcn_mfma_f32_16x16x32_bf16(
                    qf[kh], kf, s[ni], 0, 0, 0);
            }

        // online softmax (row = (l>>4)*4+rg, 16 lanes/row share via shfl)
#pragma unroll
        for (int rg = 0; rg < 4; ++rg) {
            float s0 = s[0][rg], s1 = s[1][rg], s2 = s[2][rg], s3 = s[3][rg];
            float mx = fmaxf(fmaxf(s0, s1), fmaxf(s2, s3));
#pragma unroll
            for (int off = 1; off < 16; off <<= 1)
                mx = fmaxf(mx, __shfl_xor(mx, off, 64));
            const float mnew = fmaxf(mrow[rg], mx);
            const float alpha = __expf(mrow[rg] - mnew);
            float p0 = __expf(s0 - mnew), p1 = __expf(s1 - mnew);
            float p2 = __expf(s2 - mnew), p3 = __expf(s3 - mnew);
            float rs = p0 + p1 + p2 + p3;
#pragma unroll
            for (int off = 1; off < 16; off <<= 1)
                rs += __shfl_xor(rs, off, 64);
            lrow[rg] = lrow[rg] * alpha + rs;
            mrow[rg] = mnew;
#pragma unroll
            for (int ni = 0; ni < 4; ++ni) o[ni][rg] *= alpha;
            const int rq = (l >> 4) * 4 + rg;
            const int kb = l & 15;
            pw[rq * 64 + ((((0 * 16 + kb) >> 3) ^ (rq & 7)) * 8) + (kb & 7)] = f2bf(p0);
            pw[rq * 64 + ((((1 * 16 + kb) >> 3) ^ (rq & 7)) * 8) + (kb & 7)] = f2bf(p1);
            pw[rq * 64 + ((((2 * 16 + kb) >> 3) ^ (rq & 7)) * 8) + (kb & 7)] = f2bf(p2);
            pw[rq * 64 + ((((3 * 16 + kb) >> 3) ^ (rq & 7)) * 8) + (kb & 7)] = f2bf(p3);
        }
        asm volatile("s_waitcnt lgkmcnt(0)" ::: "memory");
        __builtin_amdgcn_sched_barrier(0);

        // O += P V  (8 MFMA)
#pragma unroll
        for (int kh = 0; kh < 2; ++kh) {
            const int rq = l & 15;
            const int chp = (kh * 4 + (l >> 4)) ^ (rq & 7);
            s16x8 pf = *(const s16x8*)(pw + rq * 64 + chp * 8);
#pragma unroll
            for (int ni = 0; ni < 4; ++ni) {
                const int d = ni * 16 + (l & 15);
                const int ch = (kh * 4 + (l >> 4)) ^ (d & 7);
                s16x8 vf = *(const s16x8*)(Vs[cur] + d * 64 + ch * 8);
                o[ni] = __builtin_amdgcn_mfma_f32_16x16x32_bf16(
                    pf, vf, o[ni], 0, 0, 0);
            }
        }
        __syncthreads();
    }

    // normalize + store bf16
#pragma unroll
    for (int rg = 0; rg < 4; ++rg) {
        const float inv = 1.f / lrow[rg];
        const size_t tok = tokbase + qt * 64 + w * 16 + (l >> 4) * 4 + rg;
#pragma unroll
        for (int ni = 0; ni < 4; ++ni)
            attn[tok * Dd + h * 64 + ni * 16 + (l & 15)] =
                f2bf(o[ni][rg] * inv);
    }
}

// ---------------------------------------------------------------------------
// fp32 -> bf16 elementwise convert, 4 elems/thread
// ---------------------------------------------------------------------------
__global__ __launch_bounds__(256) void conv_bf16(const float* __restrict__ in,
                                                 u16* __restrict__ out) {
    const int i = blockIdx.x * 256 + threadIdx.x;
    float4 v = ((const float4*)in)[i];
    s16x4 o;
    o[0] = (short)f2bf(v.x); o[1] = (short)f2bf(v.y);
    o[2] = (short)f2bf(v.z); o[3] = (short)f2bf(v.w);
    ((s16x4*)out)[i] = o;
}

// ---------------------------------------------------------------------------
// W[K][N] f32 -> Wt[N][K] bf16
// ---------------------------------------------------------------------------
__global__ __launch_bounds__(256) void transpose_w(const float* __restrict__ W,
                                                   u16* __restrict__ Wt,
                                                   int K, int N) {
    __shared__ u32 tile[64][65];
    const int n0 = blockIdx.x * 64, k0 = blockIdx.y * 64;
    const int t = threadIdx.x;
#pragma unroll
    for (int i = 0; i < 4; ++i) {
        const int flat = i * 256 + t;
        const int kr = flat >> 4, c4 = (flat & 15) * 4;
        float4 v = *(const float4*)(W + (size_t)(k0 + kr) * N + n0 + c4);
        tile[c4 + 0][kr] = (u32)f2bf(v.x);
        tile[c4 + 1][kr] = (u32)f2bf(v.y);
        tile[c4 + 2][kr] = (u32)f2bf(v.z);
        tile[c4 + 3][kr] = (u32)f2bf(v.w);
    }
    __syncthreads();
#pragma unroll
    for (int i = 0; i < 4; ++i) {
        const int flat = i * 256 + t;
        const int nr = flat >> 4, k4 = (flat & 15) * 4;
        s16x4 o;
#pragma unroll
        for (int j = 0; j < 4; ++j) o[j] = (short)tile[nr][k4 + j];
        *(s16x4*)(Wt + (size_t)(n0 + nr) * K + k0 + k4) = o;
    }
}

// ---------------------------------------------------------------------------
// V columns of qkv (bf16) -> Vtg[(bh*64+d)][s]
// ---------------------------------------------------------------------------
__global__ __launch_bounds__(256) void vtrans(const u16* __restrict__ qkv,
                                              u16* __restrict__ Vtg) {
    __shared__ u32 tile[64][65];
    const int st = blockIdx.x;
    const int bh = blockIdx.y;
    const int b = bh >> 4, h = bh & 15;
    const int t = threadIdx.x;
    const int vc = h * 192 + 128;
#pragma unroll
    for (int i = 0; i < 4; ++i) {
        const int flat = i * 256 + t;
        const int s = flat >> 4, c4 = (flat & 15) * 4;
        s16x4 v = *(const s16x4*)(qkv + ((size_t)b * Ss + st * 64 + s) * 3072 + vc + c4);
#pragma unroll
        for (int j = 0; j < 4; ++j) tile[c4 + j][s] = (u32)(u16)v[j];
    }
    __syncthreads();
#pragma unroll
    for (int i = 0; i < 4; ++i) {
        const int flat = i * 256 + t;
        const int d = flat >> 4, s4 = (flat & 15) * 4;
        s16x4 o;
#pragma unroll
        for (int j = 0; j < 4; ++j) o[j] = (short)tile[d][s4 + j];
        *(s16x4*)(Vtg + ((size_t)bh * 64 + d) * Ss + st * 64 + s4) = o;
    }
}

// ---------------------------------------------------------------------------
// out = LN(x + delta) * g + beta (f32); optionally also bf16 copy.
// ---------------------------------------------------------------------------
template <bool WB>
__global__ __launch_bounds__(256) void ln_res(
    const float* __restrict__ xin, const float* __restrict__ delta,
    const float* __restrict__ g, const float* __restrict__ beta,
    float* __restrict__ out, u16* __restrict__ outb)
{
    __shared__ float red[8];
    const int row = blockIdx.x;
    const int tid = threadIdx.x;
    const size_t ofs = (size_t)row * Dd + tid * 4;

    float4 xv = *(const float4*)(xin + ofs);
    float4 dv = *(const float4*)(delta + ofs);
    float v0 = xv.x + dv.x, v1 = xv.y + dv.y, v2 = xv.z + dv.z, v3 = xv.w + dv.w;

    float sum = v0 + v1 + v2 + v3;
#pragma unroll
    for (int off = 1; off < 64; off <<= 1) sum += __shfl_xor(sum, off, 64);
    const int wid = tid >> 6;
    if ((tid & 63) == 0) red[wid] = sum;
    __syncthreads();
    sum = red[0] + red[1] + red[2] + red[3];
    const float mean = sum * (1.f / Dd);

    float d0 = v0 - mean, d1 = v1 - mean, d2 = v2 - mean, d3 = v3 - mean;
    float s2 = d0 * d0 + d1 * d1 + d2 * d2 + d3 * d3;
#pragma unroll
    for (int off = 1; off < 64; off <<= 1) s2 += __shfl_xor(s2, off, 64);
    if ((tid & 63) == 0) red[4 + wid] = s2;
    __syncthreads();
    s2 = red[4] + red[5] + red[6] + red[7];
    const float rstd = rsqrtf(s2 * (1.f / Dd) + 1e-5f);

    float4 gv = *(const float4*)(g + (size_t)tid * 4);
    float4 bv = *(const float4*)(beta + (size_t)tid * 4);
    float4 ov;
    ov.x = d0 * rstd * gv.x + bv.x;
    ov.y = d1 * rstd * gv.y + bv.y;
    ov.z = d2 * rstd * gv.z + bv.z;
    ov.w = d3 * rstd * gv.w + bv.w;
    *(float4*)(out + ofs) = ov;
    if (WB) {
        s16x4 ob;
        ob[0] = (short)f2bf(ov.x); ob[1] = (short)f2bf(ov.y);
        ob[2] = (short)f2bf(ov.z); ob[3] = (short)f2bf(ov.w);
        *(s16x4*)(outb + ofs) = ob;
    }
}

// ---------------------------------------------------------------------------
// Workspace arena (byte offsets; liveness-checked, same as round 2):
//  x1f @0 16.78M | x1b @16.78M 8.39M | W1T @25.17M 8.39M | W2T @33.55M 8.39M
//  xb @41.94M | WqkvT @50.33M | WoT @56.62M | qkv @58.72M 25.17M
//  Vtg @83.89M | attnB @92.27M | proj @58.72M f32 | ff1 @41.94M | tmp2 @75.50M
// ---------------------------------------------------------------------------
extern "C" void kernel_launch(void* const* d_in, const int* in_sizes, int n_in,
                              void* d_out, int out_size, void* d_ws, size_t ws_size,
                              hipStream_t stream)
{
    (void)in_sizes; (void)n_in; (void)out_size; (void)ws_size;
    const float* x    = (const float*)d_in[0];
    const float* Wqkv = (const float*)d_in[1];
    const float* bqkv = (const float*)d_in[2];
    const float* Wo   = (const float*)d_in[3];
    const float* bo   = (const float*)d_in[4];
    const float* W1   = (const float*)d_in[5];
    const float* b1   = (const float*)d_in[6];
    const float* W2   = (const float*)d_in[7];
    const float* b2   = (const float*)d_in[8];
    const float* g1   = (const float*)d_in[9];
    const float* be1  = (const float*)d_in[10];
    const float* g2   = (const float*)d_in[11];
    const float* be2  = (const float*)d_in[12];

    char* ws = (char*)d_ws;
    float* x1f   = (float*)(ws + 0);
    u16*   x1b   = (u16*)(ws + 16777216);
    u16*   W1T   = (u16*)(ws + 25165824);
    u16*   W2T   = (u16*)(ws + 33554432);
    u16*   xb    = (u16*)(ws + 41943040);
    u16*   WqkvT = (u16*)(ws + 50331648);
    u16*   WoT   = (u16*)(ws + 56623104);
    u16*   qkv   = (u16*)(ws + 58720256);
    u16*   Vtg   = (u16*)(ws + 83886080);
    u16*   attnB = (u16*)(ws + 92274688);
    float* proj  = (float*)(ws + 58720256);
    u16*   ff1   = (u16*)(ws + 41943040);
    float* tmp2  = (float*)(ws + 75497472);

    dim3 blk(256);

    // 0. converts / transposes
    conv_bf16<<<Mm * Dd / 4 / 256, blk, 0, stream>>>(x, xb);
    transpose_w<<<dim3(3 * Dd / 64, Dd / 64), blk, 0, stream>>>(Wqkv, WqkvT, Dd, 3 * Dd);
    transpose_w<<<dim3(Dd / 64, Dd / 64), blk, 0, stream>>>(Wo, WoT, Dd, Dd);
    transpose_w<<<dim3(Ff / 64, Dd / 64), blk, 0, stream>>>(W1, W1T, Dd, Ff);
    transpose_w<<<dim3(Dd / 64, Ff / 64), blk, 0, stream>>>(W2, W2T, Ff, Dd);

    // 1. qkv = xb @ WqkvT^T + bqkv      [4096,3072] bf16, 128^2, grid 768
    gemm_pipe<128, 128, 2, 2, true, false>
        <<<dim3(3 * Dd / 128, Mm / 128), blk, 0, stream>>>(
        xb, WqkvT, bqkv, qkv, Mm, 3 * Dd, Dd);

    // 2. Vtg = transpose(V part of qkv)
    vtrans<<<dim3(Ss / 64, Bb * Hh), blk, 0, stream>>>(qkv, Vtg);

    // 3. attnB = flash_attention(qkv, Vtg)   [4096,1024] bf16, grid 1024
    attn_mfma<<<dim3(Ss / 64, Bb * Hh), blk, 0, stream>>>(qkv, Vtg, attnB);

    // 4. proj = attnB @ WoT^T + bo       [4096,1024] f32, 128^2, grid 256
    gemm_pipe<128, 128, 2, 2, false, false>
        <<<dim3(Dd / 128, Mm / 128), blk, 0, stream>>>(
        attnB, WoT, bo, proj, Mm, Dd, Dd);

    // 5. x1f/x1b = LN(x + proj)
    ln_res<true><<<Mm, blk, 0, stream>>>(x, proj, g1, be1, x1f, x1b);

    // 6. ff1 = gelu(x1b @ W1T^T + b1)    [4096,4096] bf16, 256^2, grid 256
    gemm_pipe<256, 256, 2, 4, true, true>
        <<<dim3(Ff / 256, Mm / 256), dim3(512), 0, stream>>>(
        x1b, W1T, b1, ff1, Mm, Ff, Dd);

    // 7. tmp2 = ff1 @ W2T^T + b2         [4096,1024] f32, 128^2, grid 256
    gemm_pipe<128, 128, 2, 2, false, false>
        <<<dim3(Dd / 128, Mm / 128), blk, 0, stream>>>(
        ff1, W2T, b2, tmp2, Mm, Dd, Ff);

    // 8. out = LN(x1f + tmp2)
    ln_res<false><<<Mm, blk, 0, stream>>>(x1f, tmp2, g2, be2, (float*)d_out, nullptr);
}

// Round 6
// 376.814 us; speedup vs baseline: 6.0325x; 1.1495x over previous
//
#include <hip/hip_runtime.h>
#include <hip/hip_bf16.h>

typedef unsigned int u32;
typedef unsigned short u16;
typedef __attribute__((ext_vector_type(4))) float f32x4;
typedef __attribute__((ext_vector_type(8))) short s16x8;
typedef __attribute__((ext_vector_type(4))) short s16x4;
typedef __attribute__((ext_vector_type(2))) unsigned int u32x2;

constexpr int Bb = 2, Ss = 2048, Dd = 1024, Ff = 4096, Hh = 16, HD = 64;
constexpr int Mm = Bb * Ss;  // 4096 token rows

// ---------------- helpers ----------------
__device__ __forceinline__ u16 f2bf(float f) {
    u32 u = __builtin_bit_cast(u32, f);
    u32 r = (u + 0x7FFFu + ((u >> 16) & 1u)) >> 16;   // RNE
    return (u16)r;
}
__device__ __forceinline__ float bf2f(u16 b) {
    u32 u = ((u32)b) << 16;
    return __builtin_bit_cast(float, u);
}
__device__ __forceinline__ u32 cvtpk_bf16(float lo, float hi) {
    u32 r;
    asm("v_cvt_pk_bf16_f32 %0, %1, %2" : "=v"(r) : "v"(lo), "v"(hi));
    return r;  // D[15:0]=bf16(lo), D[31:16]=bf16(hi), RNE
}
__device__ __forceinline__ float gelu_exact(float x) {
    return 0.5f * x * (1.0f + erff(x * 0.70710678118654752f));
}
// async global->LDS, 16B/lane. LDS dest wave-uniform (HW adds lane*16);
// global source per-lane.
__device__ __forceinline__ void gload16(const void* g, void* l) {
    __builtin_amdgcn_global_load_lds(
        (const __attribute__((address_space(1))) u32*)g,
        (__attribute__((address_space(3))) u32*)l, 16, 0, 0);
}

// ---------------------------------------------------------------------------
// Pipelined bf16 MFMA GEMM: C = A[M,K] @ Bt[N,K]^T + bias (opt GELU).
// BK=32, triple-buffered LDS, counted vmcnt(4) (T4), chunk-XOR swizzle (T2),
// setprio around MFMA (T5). Unchanged from round 4 (verified).
// ---------------------------------------------------------------------------
template <int BM, int BN, int WM, int WN, bool OUT_BF16, bool GELU>
__global__ __launch_bounds__(WM * WN * 64, (WM * WN == 8) ? 2 : 3)
void gemm_pipe(const u16* __restrict__ A, const u16* __restrict__ Bt,
               const float* __restrict__ bias, void* __restrict__ C,
               int M, int N, int K)
{
    constexpr int NWAVE = WM * WN;
    constexpr int THREADS = NWAVE * 64;
    constexpr int MREP = BM / (WM * 16);
    constexpr int NREP = BN / (WN * 16);
    constexpr int ATILE = BM * 32;      // u16 elements per A tile
    constexpr int BTILE = BN * 32;
    constexpr int STEP = ATILE + BTILE;
    __shared__ __align__(16) u16 lds[3 * STEP];

    const int tid = threadIdx.x;
    const int l = tid & 63;
    const int w = tid >> 6;
    const int wr = w / WN, wc = w % WN;
    const int brow = blockIdx.y * BM, bcol = blockIdx.x * BN;
    const int nt = K / 32;

    f32x4 acc[MREP][NREP];
#pragma unroll
    for (int i = 0; i < MREP; ++i)
#pragma unroll
        for (int j = 0; j < NREP; ++j) acc[i][j] = (f32x4){0.f, 0.f, 0.f, 0.f};

    const u16* gA[2]; const u16* gB[2];
#pragma unroll
    for (int i = 0; i < 2; ++i) {
        const int flat = i * THREADS + tid;
        const int r = flat >> 2;
        const int lc = (flat & 3) ^ ((r ^ (r >> 2)) & 3);
        gA[i] = A + (size_t)(brow + r) * K + lc * 8;
        gB[i] = Bt + (size_t)(bcol + r) * K + lc * 8;
    }

    int aoff[MREP], boff[NREP];
#pragma unroll
    for (int mi = 0; mi < MREP; ++mi) {
        const int r = wr * (MREP * 16) + mi * 16 + (l & 15);
        aoff[mi] = r * 32 + (((l >> 4) ^ ((r ^ (r >> 2)) & 3)) * 8);
    }
#pragma unroll
    for (int ni = 0; ni < NREP; ++ni) {
        const int r = wc * (NREP * 16) + ni * 16 + (l & 15);
        boff[ni] = r * 32 + (((l >> 4) ^ ((r ^ (r >> 2)) & 3)) * 8);
    }

    auto stage = [&](int s, int t) {
        u16* base = lds + s * STEP;
#pragma unroll
        for (int i = 0; i < 2; ++i)
            gload16(gA[i] + t * 32, base + i * THREADS * 8 + w * 512);
#pragma unroll
        for (int i = 0; i < 2; ++i)
            gload16(gB[i] + t * 32, base + ATILE + i * THREADS * 8 + w * 512);
    };

    stage(0, 0);
    stage(1, 1);
    asm volatile("s_waitcnt vmcnt(4)" ::: "memory");
    __builtin_amdgcn_s_barrier();

    int cur = 0;
    for (int t = 0; t < nt; ++t) {
        if (t + 2 < nt) stage((cur + 2 >= 3) ? cur - 1 : cur + 2, t + 2);

        const u16* Ab = lds + cur * STEP;
        const u16* Bbs = Ab + ATILE;
        s16x8 af[MREP], bfr[NREP];
#pragma unroll
        for (int mi = 0; mi < MREP; ++mi) af[mi] = *(const s16x8*)(Ab + aoff[mi]);
#pragma unroll
        for (int ni = 0; ni < NREP; ++ni) bfr[ni] = *(const s16x8*)(Bbs + boff[ni]);

        __builtin_amdgcn_s_setprio(1);
#pragma unroll
        for (int mi = 0; mi < MREP; ++mi)
#pragma unroll
            for (int ni = 0; ni < NREP; ++ni)
                acc[mi][ni] = __builtin_amdgcn_mfma_f32_16x16x32_bf16(
                    af[mi], bfr[ni], acc[mi][ni], 0, 0, 0);
        __builtin_amdgcn_s_setprio(0);

        if (t + 1 < nt) {
            if (t + 2 < nt) {
                asm volatile("s_waitcnt vmcnt(4)" ::: "memory");  // t+1 landed
            } else {
                asm volatile("s_waitcnt vmcnt(0)" ::: "memory");  // drain
            }
            __builtin_amdgcn_s_barrier();
        }
        cur = (cur + 1 >= 3) ? 0 : cur + 1;
    }

    asm volatile("" ::: "memory");
    float bc[NREP];
#pragma unroll
    for (int ni = 0; ni < NREP; ++ni)
        bc[ni] = bias[bcol + wc * (NREP * 16) + ni * 16 + (l & 15)];
#pragma unroll
    for (int mi = 0; mi < MREP; ++mi) {
        const int row0 = brow + wr * (MREP * 16) + mi * 16 + (l >> 4) * 4;
#pragma unroll
        for (int ni = 0; ni < NREP; ++ni) {
            const int col = bcol + wc * (NREP * 16) + ni * 16 + (l & 15);
#pragma unroll
            for (int rg = 0; rg < 4; ++rg) {
                float v = acc[mi][ni][rg] + bc[ni];
                if (GELU) v = gelu_exact(v);
                if (OUT_BF16)
                    ((u16*)C)[(size_t)(row0 + rg) * N + col] = f2bf(v);
                else
                    ((float*)C)[(size_t)(row0 + rg) * N + col] = v;
            }
        }
    }
}

// ---------------------------------------------------------------------------
// Flash attention, bf16 MFMA, SWAPPED-operand in-register softmax.
// qkv[token][3072] (head h: q|k|v @ h*192); Vtg[(bh*64+d)][s] pre-transposed V.
// Block = 64 q-rows x (b,h); 4 waves, wave w owns q rows w*16..+16.
// S^T = mfma(K, Q): lane (q=l&15, g=l>>4) holds S[key=16ni+4g+rg][q] -> each
// lane owns 16 P-values of ONE q-row => in-lane softmax + 2 shfl_xor (16,32).
// P packed via v_cvt_pk_bf16_f32, written as 4x ds_write_b64 into the
// XOR-swizzled per-wave P buffer (read pattern = round-2's 0-conflict one).
// O^T = mfma(V^T, P): D[m=d][n=q], col = q = l&15 matches softmax lane.
// K/V double-buffered, 2-phase prefetch (drain at __syncthreads).
// ---------------------------------------------------------------------------
__global__ __launch_bounds__(256, 4) void attn_mfma(
    const u16* __restrict__ qkv, const u16* __restrict__ Vtg,
    u16* __restrict__ attn)
{
    __shared__ __align__(16) u16 Ks[2][64 * 64];   // [key][d]
    __shared__ __align__(16) u16 Vs[2][64 * 64];   // [d][key]
    __shared__ __align__(16) u16 Ps[4][16 * 64];   // per-wave [q][key]
    const int tid = threadIdx.x, l = tid & 63, w = tid >> 6;
    const int q = l & 15, g = l >> 4;
    const int qt = blockIdx.x;           // 0..31
    const int bh = blockIdx.y;           // 0..31
    const int b = bh >> 4, h = bh & 15;
    const size_t tokbase = (size_t)b * Ss;
    const int qc = h * 192, kc = qc + 64;

    // Q fragments (B-operand: lane n=q, k=d=g*8+j+32*kh), scaled by 1/8
    s16x8 qf[2];
    {
        const int row = qt * 64 + w * 16 + q;
        const u16* qp = qkv + (tokbase + row) * 3072 + qc + g * 8;
#pragma unroll
        for (int kh = 0; kh < 2; ++kh) {
            s16x8 v = *(const s16x8*)(qp + kh * 32);
#pragma unroll
            for (int j = 0; j < 8; ++j)
                v[j] = (short)f2bf(bf2f((u16)v[j]) * 0.125f);
            qf[kh] = v;
        }
    }

    float mrow = -1e30f, lrow = 0.f;     // per-lane: this lane's q-row state
    f32x4 o[4];
#pragma unroll
    for (int ni = 0; ni < 4; ++ni) o[ni] = (f32x4){0.f, 0.f, 0.f, 0.f};

    // K/V staging (unchanged): issue i covers rows flat>>3, chunk (flat&7)^(row&7)
    int srow[2], slc[2];
#pragma unroll
    for (int i = 0; i < 2; ++i) {
        const int flat = i * 256 + tid;
        srow[i] = flat >> 3;
        slc[i] = (flat & 7) ^ (srow[i] & 7);
    }
    u16* pw = Ps[w];

    // P write offsets: lane holds keys 16ni+4g+rg (4 consecutive) ->
    // 8B half-chunk: chunk = 2ni+(g>>1), half = g&1; swizzle chunk ^= (q&7).
    int pwr[4];
#pragma unroll
    for (int ni = 0; ni < 4; ++ni)
        pwr[ni] = q * 64 + (((2 * ni + (g >> 1)) ^ (q & 7)) * 8) + (g & 1) * 4;
    // P read offsets (B-operand: lane n=q, keys kh*32+g*8..+7)
    int prd[2];
#pragma unroll
    for (int kh = 0; kh < 2; ++kh)
        prd[kh] = q * 64 + (((kh * 4 + g) ^ (q & 7)) * 8);

    auto stageKV = [&](int s, int kt) {
        const size_t krow = tokbase + kt * 64;
#pragma unroll
        for (int i = 0; i < 2; ++i)
            gload16(qkv + (krow + srow[i]) * 3072 + kc + slc[i] * 8,
                    Ks[s] + i * 2048 + w * 512);
#pragma unroll
        for (int i = 0; i < 2; ++i)
            gload16(Vtg + (size_t)(bh * 64 + srow[i]) * Ss + kt * 64 + slc[i] * 8,
                    Vs[s] + i * 2048 + w * 512);
    };

    stageKV(0, 0);
    __syncthreads();

    for (int kt = 0; kt < Ss / 64; ++kt) {
        const int cur = kt & 1;
        if (kt + 1 < Ss / 64) stageKV(cur ^ 1, kt + 1);

        // S^T = mfma(K, Q): s[ni][rg] = S[key=16ni+4g+rg][q]
        f32x4 s[4];
#pragma unroll
        for (int ni = 0; ni < 4; ++ni) s[ni] = (f32x4){0.f, 0.f, 0.f, 0.f};
#pragma unroll
        for (int kh = 0; kh < 2; ++kh)
#pragma unroll
            for (int ni = 0; ni < 4; ++ni) {
                const int key = ni * 16 + q;
                const int ch = (kh * 4 + g) ^ (key & 7);
                s16x8 kf = *(const s16x8*)(Ks[cur] + key * 64 + ch * 8);
                s[ni] = __builtin_amdgcn_mfma_f32_16x16x32_bf16(
                    kf, qf[kh], s[ni], 0, 0, 0);
            }

        // ---- in-register online softmax over this lane's q-row ----
        float mx = s[0][0];
#pragma unroll
        for (int ni = 0; ni < 4; ++ni)
#pragma unroll
            for (int rg = 0; rg < 4; ++rg) mx = fmaxf(mx, s[ni][rg]);
        mx = fmaxf(mx, __shfl_xor(mx, 16, 64));
        mx = fmaxf(mx, __shfl_xor(mx, 32, 64));
        const float mnew = fmaxf(mrow, mx);
        const float alpha = __expf(mrow - mnew);
        float p[4][4];
        float rs = 0.f;
#pragma unroll
        for (int ni = 0; ni < 4; ++ni)
#pragma unroll
            for (int rg = 0; rg < 4; ++rg) {
                p[ni][rg] = __expf(s[ni][rg] - mnew);
                rs += p[ni][rg];
            }
        rs += __shfl_xor(rs, 16, 64);
        rs += __shfl_xor(rs, 32, 64);
        lrow = lrow * alpha + rs;
        mrow = mnew;
#pragma unroll
        for (int ni = 0; ni < 4; ++ni) {
            o[ni][0] *= alpha; o[ni][1] *= alpha;
            o[ni][2] *= alpha; o[ni][3] *= alpha;
        }
        // pack p -> bf16 pairs, 4x ds_write_b64
#pragma unroll
        for (int ni = 0; ni < 4; ++ni) {
            u32x2 pkv;
            pkv[0] = cvtpk_bf16(p[ni][0], p[ni][1]);
            pkv[1] = cvtpk_bf16(p[ni][2], p[ni][3]);
            *(u32x2*)(pw + pwr[ni]) = pkv;
        }
        asm volatile("s_waitcnt lgkmcnt(0)" ::: "memory");
        __builtin_amdgcn_sched_barrier(0);

        // O^T += mfma(V^T, P): o[ni] = O[d=16ni+4g+rg][q]
#pragma unroll
        for (int kh = 0; kh < 2; ++kh) {
            s16x8 pb = *(const s16x8*)(pw + prd[kh]);
#pragma unroll
            for (int ni = 0; ni < 4; ++ni) {
                const int d = ni * 16 + q;
                const int ch = (kh * 4 + g) ^ (d & 7);
                s16x8 vf = *(const s16x8*)(Vs[cur] + d * 64 + ch * 8);
                o[ni] = __builtin_amdgcn_mfma_f32_16x16x32_bf16(
                    vf, pb, o[ni], 0, 0, 0);
            }
        }
        __syncthreads();
    }

    // normalize + store: lane owns q-row q=l&15; d = 16ni + 4g + rg
    const float inv = 1.f / lrow;
    const size_t tok = tokbase + qt * 64 + w * 16 + q;
#pragma unroll
    for (int ni = 0; ni < 4; ++ni) {
        s16x4 ov;
#pragma unroll
        for (int rg = 0; rg < 4; ++rg) ov[rg] = (short)f2bf(o[ni][rg] * inv);
        *(s16x4*)(attn + tok * Dd + h * 64 + ni * 16 + g * 4) = ov;
    }
}

// ---------------------------------------------------------------------------
// fp32 -> bf16 elementwise convert, 4 elems/thread
// ---------------------------------------------------------------------------
__global__ __launch_bounds__(256) void conv_bf16(const float* __restrict__ in,
                                                 u16* __restrict__ out) {
    const int i = blockIdx.x * 256 + threadIdx.x;
    float4 v = ((const float4*)in)[i];
    s16x4 o;
    o[0] = (short)f2bf(v.x); o[1] = (short)f2bf(v.y);
    o[2] = (short)f2bf(v.z); o[3] = (short)f2bf(v.w);
    ((s16x4*)out)[i] = o;
}

// ---------------------------------------------------------------------------
// W[K][N] f32 -> Wt[N][K] bf16
// ---------------------------------------------------------------------------
__global__ __launch_bounds__(256) void transpose_w(const float* __restrict__ W,
                                                   u16* __restrict__ Wt,
                                                   int K, int N) {
    __shared__ u32 tile[64][65];
    const int n0 = blockIdx.x * 64, k0 = blockIdx.y * 64;
    const int t = threadIdx.x;
#pragma unroll
    for (int i = 0; i < 4; ++i) {
        const int flat = i * 256 + t;
        const int kr = flat >> 4, c4 = (flat & 15) * 4;
        float4 v = *(const float4*)(W + (size_t)(k0 + kr) * N + n0 + c4);
        tile[c4 + 0][kr] = (u32)f2bf(v.x);
        tile[c4 + 1][kr] = (u32)f2bf(v.y);
        tile[c4 + 2][kr] = (u32)f2bf(v.z);
        tile[c4 + 3][kr] = (u32)f2bf(v.w);
    }
    __syncthreads();
#pragma unroll
    for (int i = 0; i < 4; ++i) {
        const int flat = i * 256 + t;
        const int nr = flat >> 4, k4 = (flat & 15) * 4;
        s16x4 o;
#pragma unroll
        for (int j = 0; j < 4; ++j) o[j] = (short)tile[nr][k4 + j];
        *(s16x4*)(Wt + (size_t)(n0 + nr) * K + k0 + k4) = o;
    }
}

// ---------------------------------------------------------------------------
// V columns of qkv (bf16) -> Vtg[(bh*64+d)][s]
// ---------------------------------------------------------------------------
__global__ __launch_bounds__(256) void vtrans(const u16* __restrict__ qkv,
                                              u16* __restrict__ Vtg) {
    __shared__ u32 tile[64][65];
    const int st = blockIdx.x;
    const int bh = blockIdx.y;
    const int b = bh >> 4, h = bh & 15;
    const int t = threadIdx.x;
    const int vc = h * 192 + 128;
#pragma unroll
    for (int i = 0; i < 4; ++i) {
        const int flat = i * 256 + t;
        const int s = flat >> 4, c4 = (flat & 15) * 4;
        s16x4 v = *(const s16x4*)(qkv + ((size_t)b * Ss + st * 64 + s) * 3072 + vc + c4);
#pragma unroll
        for (int j = 0; j < 4; ++j) tile[c4 + j][s] = (u32)(u16)v[j];
    }
    __syncthreads();
#pragma unroll
    for (int i = 0; i < 4; ++i) {
        const int flat = i * 256 + t;
        const int d = flat >> 4, s4 = (flat & 15) * 4;
        s16x4 o;
#pragma unroll
        for (int j = 0; j < 4; ++j) o[j] = (short)tile[d][s4 + j];
        *(s16x4*)(Vtg + ((size_t)bh * 64 + d) * Ss + st * 64 + s4) = o;
    }
}

// ---------------------------------------------------------------------------
// out = LN(x + delta) * g + beta (f32); optionally also bf16 copy.
// ---------------------------------------------------------------------------
template <bool WB>
__global__ __launch_bounds__(256) void ln_res(
    const float* __restrict__ xin, const float* __restrict__ delta,
    const float* __restrict__ g, const float* __restrict__ beta,
    float* __restrict__ out, u16* __restrict__ outb)
{
    __shared__ float red[8];
    const int row = blockIdx.x;
    const int tid = threadIdx.x;
    const size_t ofs = (size_t)row * Dd + tid * 4;

    float4 xv = *(const float4*)(xin + ofs);
    float4 dv = *(const float4*)(delta + ofs);
    float v0 = xv.x + dv.x, v1 = xv.y + dv.y, v2 = xv.z + dv.z, v3 = xv.w + dv.w;

    float sum = v0 + v1 + v2 + v3;
#pragma unroll
    for (int off = 1; off < 64; off <<= 1) sum += __shfl_xor(sum, off, 64);
    const int wid = tid >> 6;
    if ((tid & 63) == 0) red[wid] = sum;
    __syncthreads();
    sum = red[0] + red[1] + red[2] + red[3];
    const float mean = sum * (1.f / Dd);

    float d0 = v0 - mean, d1 = v1 - mean, d2 = v2 - mean, d3 = v3 - mean;
    float s2 = d0 * d0 + d1 * d1 + d2 * d2 + d3 * d3;
#pragma unroll
    for (int off = 1; off < 64; off <<= 1) s2 += __shfl_xor(s2, off, 64);
    if ((tid & 63) == 0) red[4 + wid] = s2;
    __syncthreads();
    s2 = red[4] + red[5] + red[6] + red[7];
    const float rstd = rsqrtf(s2 * (1.f / Dd) + 1e-5f);

    float4 gv = *(const float4*)(g + (size_t)tid * 4);
    float4 bv = *(const float4*)(beta + (size_t)tid * 4);
    float4 ov;
    ov.x = d0 * rstd * gv.x + bv.x;
    ov.y = d1 * rstd * gv.y + bv.y;
    ov.z = d2 * rstd * gv.z + bv.z;
    ov.w = d3 * rstd * gv.w + bv.w;
    *(float4*)(out + ofs) = ov;
    if (WB) {
        s16x4 ob;
        ob[0] = (short)f2bf(ov.x); ob[1] = (short)f2bf(ov.y);
        ob[2] = (short)f2bf(ov.z); ob[3] = (short)f2bf(ov.w);
        *(s16x4*)(outb + ofs) = ob;
    }
}

// ---------------------------------------------------------------------------
// Workspace arena (byte offsets; liveness-checked, same as round 2):
//  x1f @0 16.78M | x1b @16.78M 8.39M | W1T @25.17M 8.39M | W2T @33.55M 8.39M
//  xb @41.94M | WqkvT @50.33M | WoT @56.62M | qkv @58.72M 25.17M
//  Vtg @83.89M | attnB @92.27M | proj @58.72M f32 | ff1 @41.94M | tmp2 @75.50M
// ---------------------------------------------------------------------------
extern "C" void kernel_launch(void* const* d_in, const int* in_sizes, int n_in,
                              void* d_out, int out_size, void* d_ws, size_t ws_size,
                              hipStream_t stream)
{
    (void)in_sizes; (void)n_in; (void)out_size; (void)ws_size;
    const float* x    = (const float*)d_in[0];
    const float* Wqkv = (const float*)d_in[1];
    const float* bqkv = (const float*)d_in[2];
    const float* Wo   = (const float*)d_in[3];
    const float* bo   = (const float*)d_in[4];
    const float* W1   = (const float*)d_in[5];
    const float* b1   = (const float*)d_in[6];
    const float* W2   = (const float*)d_in[7];
    const float* b2   = (const float*)d_in[8];
    const float* g1   = (const float*)d_in[9];
    const float* be1  = (const float*)d_in[10];
    const float* g2   = (const float*)d_in[11];
    const float* be2  = (const float*)d_in[12];

    char* ws = (char*)d_ws;
    float* x1f   = (float*)(ws + 0);
    u16*   x1b   = (u16*)(ws + 16777216);
    u16*   W1T   = (u16*)(ws + 25165824);
    u16*   W2T   = (u16*)(ws + 33554432);
    u16*   xb    = (u16*)(ws + 41943040);
    u16*   WqkvT = (u16*)(ws + 50331648);
    u16*   WoT   = (u16*)(ws + 56623104);
    u16*   qkv   = (u16*)(ws + 58720256);
    u16*   Vtg   = (u16*)(ws + 83886080);
    u16*   attnB = (u16*)(ws + 92274688);
    float* proj  = (float*)(ws + 58720256);
    u16*   ff1   = (u16*)(ws + 41943040);
    float* tmp2  = (float*)(ws + 75497472);

    dim3 blk(256);

    // 0. converts / transposes
    conv_bf16<<<Mm * Dd / 4 / 256, blk, 0, stream>>>(x, xb);
    transpose_w<<<dim3(3 * Dd / 64, Dd / 64), blk, 0, stream>>>(Wqkv, WqkvT, Dd, 3 * Dd);
    transpose_w<<<dim3(Dd / 64, Dd / 64), blk, 0, stream>>>(Wo, WoT, Dd, Dd);
    transpose_w<<<dim3(Ff / 64, Dd / 64), blk, 0, stream>>>(W1, W1T, Dd, Ff);
    transpose_w<<<dim3(Dd / 64, Ff / 64), blk, 0, stream>>>(W2, W2T, Ff, Dd);

    // 1. qkv = xb @ WqkvT^T + bqkv      [4096,3072] bf16, 128^2, grid 768
    gemm_pipe<128, 128, 2, 2, true, false>
        <<<dim3(3 * Dd / 128, Mm / 128), blk, 0, stream>>>(
        xb, WqkvT, bqkv, qkv, Mm, 3 * Dd, Dd);

    // 2. Vtg = transpose(V part of qkv)
    vtrans<<<dim3(Ss / 64, Bb * Hh), blk, 0, stream>>>(qkv, Vtg);

    // 3. attnB = flash_attention(qkv, Vtg)   [4096,1024] bf16, grid 1024
    attn_mfma<<<dim3(Ss / 64, Bb * Hh), blk, 0, stream>>>(qkv, Vtg, attnB);

    // 4. proj = attnB @ WoT^T + bo       [4096,1024] f32, 128^2, grid 256
    gemm_pipe<128, 128, 2, 2, false, false>
        <<<dim3(Dd / 128, Mm / 128), blk, 0, stream>>>(
        attnB, WoT, bo, proj, Mm, Dd, Dd);

    // 5. x1f/x1b = LN(x + proj)
    ln_res<true><<<Mm, blk, 0, stream>>>(x, proj, g1, be1, x1f, x1b);

    // 6. ff1 = gelu(x1b @ W1T^T + b1)    [4096,4096] bf16, 256^2, grid 256
    gemm_pipe<256, 256, 2, 4, true, true>
        <<<dim3(Ff / 256, Mm / 256), dim3(512), 0, stream>>>(
        x1b, W1T, b1, ff1, Mm, Ff, Dd);

    // 7. tmp2 = ff1 @ W2T^T + b2         [4096,1024] f32, 128^2, grid 256
    gemm_pipe<128, 128, 2, 2, false, false>
        <<<dim3(Dd / 128, Mm / 128), blk, 0, stream>>>(
        ff1, W2T, b2, tmp2, Mm, Dd, Ff);

    // 8. out = LN(x1f + tmp2)
    ln_res<false><<<Mm, blk, 0, stream>>>(x1f, tmp2, g2, be2, (float*)d_out, nullptr);
}